// Round 15
// baseline (222.047 us; speedup 1.0000x reference)
//
#include <hip/hip_runtime.h>
#include <stdint.h>
#include <math.h>

typedef unsigned short u16;
typedef float f32x4 __attribute__((ext_vector_type(4)));
typedef __bf16 bf16x8 __attribute__((ext_vector_type(8)));

__device__ __forceinline__ u16 f2bf(float f) {
    union { float f; uint32_t u; } c; c.f = f;
    return (u16)((c.u + 0x7FFFu + ((c.u >> 16) & 1u)) >> 16);
}

__device__ __forceinline__ void gload_lds16(const void* g, void* l) {
    __builtin_amdgcn_global_load_lds(
        (const __attribute__((address_space(1))) unsigned int*)g,
        (__attribute__((address_space(3))) unsigned int*)l, 16, 0, 0);
}

// --------- fused prep: LN (blocks 0..4095) + w_qkv transpose (next 3072)
// --------- + w_proj transpose (last 1024). All roles block-uniform.
__global__ __launch_bounds__(256) void prep_kernel(const float* __restrict__ z,
                                                   const float* __restrict__ sc,
                                                   const float* __restrict__ bs,
                                                   const float* __restrict__ w_qkv,
                                                   const float* __restrict__ w_proj,
                                                   u16* __restrict__ zn,
                                                   u16* __restrict__ wqkvT,
                                                   u16* __restrict__ wprojT) {
    __shared__ float t[32][33];
    const int tid = threadIdx.x;
    const int bid = blockIdx.x;

    if (bid < 4096) {                      // ---- LayerNorm row
        float* red = &t[0][0];
        const int row = bid;
        const float4 v = ((const float4*)(z + (size_t)row * 1024))[tid];
        float s = v.x + v.y + v.z + v.w;
        #pragma unroll
        for (int off = 32; off > 0; off >>= 1) s += __shfl_xor(s, off);
        if ((tid & 63) == 0) red[tid >> 6] = s;
        __syncthreads();
        const float mean = (red[0] + red[1] + red[2] + red[3]) * (1.0f / 1024.0f);
        const float dx = v.x - mean, dy = v.y - mean, dz = v.z - mean, dw = v.w - mean;
        float q = dx * dx + dy * dy + dz * dz + dw * dw;
        #pragma unroll
        for (int off = 32; off > 0; off >>= 1) q += __shfl_xor(q, off);
        if ((tid & 63) == 0) red[4 + (tid >> 6)] = q;
        __syncthreads();
        const float var = (red[4] + red[5] + red[6] + red[7]) * (1.0f / 1024.0f);
        const float rstd = rsqrtf(var + 1e-5f);
        const float4 scv = ((const float4*)sc)[tid];
        const float4 bsv = ((const float4*)bs)[tid];
        const u16 o0 = f2bf(dx * rstd * scv.x + bsv.x);
        const u16 o1 = f2bf(dy * rstd * scv.y + bsv.y);
        const u16 o2 = f2bf(dz * rstd * scv.z + bsv.z);
        const u16 o3 = f2bf(dw * rstd * scv.w + bsv.w);
        uint2 pk;
        pk.x = (uint32_t)o0 | ((uint32_t)o1 << 16);
        pk.y = (uint32_t)o2 | ((uint32_t)o3 << 16);
        *(uint2*)&zn[(size_t)row * 1024 + tid * 4] = pk;
        return;
    }

    const float* in;
    u16* out;
    int K, N, permute, bx, by;
    if (bid < 4096 + 3072) {               // w_qkv: [1024,3072] -> permuted [3072,1024]
        const int r = bid - 4096;
        in = w_qkv; out = wqkvT; K = 1024; N = 3072; permute = 1;
        bx = r % 96; by = r / 96;
    } else {                               // w_proj: [1024,1024] -> [1024,1024]
        const int r = bid - 4096 - 3072;
        in = w_proj; out = wprojT; K = 1024; N = 1024; permute = 0;
        bx = r % 32; by = r / 32;
    }
    const int j = tid & 31, i0 = tid >> 5;
    const int kb = by * 32, nb = bx * 32;
    #pragma unroll
    for (int p = 0; p < 4; ++p) {
        int r = i0 + p * 8;
        t[r][j] = in[(size_t)(kb + r) * N + nb + j];
    }
    __syncthreads();
    #pragma unroll
    for (int p = 0; p < 4; ++p) {
        int r = i0 + p * 8;
        int c = nb + r;
        int np = c;
        if (permute) {
            int h = c / 192, rem = c - h * 192;
            int d = rem / 3, s = rem - d * 3;
            np = s * 1024 + h * 64 + d;
        }
        out[(size_t)np * K + kb + j] = f2bf(t[j][r]);
    }
}

// ---------------- GEMM1 (R6 two-barrier) + fused V transpose ---------------
// Q/K epilogue: coalesced [bh,n,d] stores (q pre-scaled 0.125*log2e).
// V epilogue (s==2 blocks): accumulator tile round-trips through padded LDS
// (stride 136 u16 -> 16B-aligned readback) and stores straight to vT[bh,d,n]
// with 16B writes. Replaces the separate transpose_v kernel.
__global__ __launch_bounds__(256) void gemm_qkv(const u16* __restrict__ A,
                                                const u16* __restrict__ Bt,
                                                u16* __restrict__ qbuf,
                                                u16* __restrict__ kbuf,
                                                u16* __restrict__ vT) {
    __shared__ __align__(16) u16 sm[64 * 136];   // 17.4 KB; main loop uses [0,8192)
    u16* const As = sm;                           // 128*32
    u16* const Bs = sm + 4096;                    // 128*32
    const int tid = threadIdx.x;
    const int wave = tid >> 6, lane = tid & 63;
    const int quad = lane >> 4, l16 = lane & 15;
    const int wm = (wave >> 1) * 64, wn = (wave & 1) * 64;
    const int row0 = blockIdx.x * 128, col0 = blockIdx.y * 128;
    const int gr = lane >> 2, gc = (lane & 3) * 8;
    f32x4 acc[4][4] = {};
    for (int kt = 0; kt < 1024; kt += 32) {
        __syncthreads();
        #pragma unroll
        for (int i = 0; i < 2; ++i) {
            const int rb = wave * 16 + i * 64;
            gload_lds16(&A[(size_t)(row0 + rb + gr) * 1024 + kt + gc], &As[rb * 32]);
            gload_lds16(&Bt[(size_t)(col0 + rb + gr) * 1024 + kt + gc], &Bs[rb * 32]);
        }
        __syncthreads();
        bf16x8 ax[4], bx[4];
        #pragma unroll
        for (int t = 0; t < 4; ++t) {
            ax[t] = *(const bf16x8*)&As[(wm + t * 16 + l16) * 32 + quad * 8];
            bx[t] = *(const bf16x8*)&Bs[(wn + t * 16 + l16) * 32 + quad * 8];
        }
        #pragma unroll
        for (int mt = 0; mt < 4; ++mt)
            #pragma unroll
            for (int nt = 0; nt < 4; ++nt)
                acc[mt][nt] = __builtin_amdgcn_mfma_f32_16x16x32_bf16(ax[mt], bx[nt], acc[mt][nt], 0, 0, 0);
    }
    const int s = col0 >> 10;                 // block-uniform
    if (s < 2) {
        u16* const dst = (s == 0) ? qbuf : kbuf;
        const float scl = (s == 0) ? 0.125f * 1.44269504088896f : 1.0f;
        #pragma unroll
        for (int mt = 0; mt < 4; ++mt) {
            #pragma unroll
            for (int nt = 0; nt < 4; ++nt) {
                #pragma unroll
                for (int e = 0; e < 4; ++e) {
                    const int row = row0 + wm + mt * 16 + quad * 4 + e;
                    const int col = col0 + wn + nt * 16 + l16;
                    const int b = row >> 11, n = row & 2047;
                    const int h = (col >> 6) & 15, d = col & 63;
                    dst[((size_t)(b * 16 + h) * 2048 + n) * 64 + d] = f2bf(acc[mt][nt][e] * scl);
                }
            }
        }
    } else {
        // V: transpose 128x128 tile through LDS, store to vT[bh,d,n].
        const int b = row0 >> 11, n0 = row0 & 2047;
        const int h0 = (col0 >> 6) & 15;          // col0 = 2048 + cb*128 -> h0 = 2*cb
        for (int hh = 0; hh < 2; ++hh) {
            __syncthreads();                      // tbuf free (main loop / prev pass done)
            if ((wave & 1) == hh) {               // wn == hh*64 waves own this col-half
                #pragma unroll
                for (int mt = 0; mt < 4; ++mt)
                    #pragma unroll
                    for (int nt = 0; nt < 4; ++nt)
                        #pragma unroll
                        for (int e = 0; e < 4; ++e) {
                            const int rl = wm + mt * 16 + quad * 4 + e;   // n-local 0..127
                            const int cl = nt * 16 + l16;                 // d 0..63
                            sm[cl * 136 + rl] = f2bf(acc[mt][nt][e]);
                        }
            }
            __syncthreads();
            const int bh = b * 16 + h0 + hh;
            #pragma unroll
            for (int pass = 0; pass < 4; ++pass) {
                const int chunk = pass * 256 + tid;   // 0..1023
                const int d = chunk >> 4;             // 0..63
                const int nc = chunk & 15;            // 16 chunks of 8 n
                const uint4 vv = *(const uint4*)&sm[d * 136 + nc * 8];
                *(uint4*)&vT[((size_t)bh * 64 + d) * 2048 + n0 + nc * 8] = vv;
            }
        }
    }
}

// ---------------- Fused flash attention (R9 proven: R6 + VGPR hint) ---------
// 128-q blocks (4 waves, 32 q each), 128-key tiles, K+V LDS dbuf (64 KB),
// one barrier/tile; stage(kt+1) flies over compute(kt). Maxless softmax
// (q pre-scaled 0.125*log2e, P=exp2(S)); denominator via MFMA against ones.
// kr-permuted K rows + XOR chunk swizzle: exp'd S^T C-layout values are the
// PV A-fragment in-lane; all LDS accesses conflict-free.
__global__ __launch_bounds__(256, 2) void attn_kernel(const u16* __restrict__ qb,
                                                      const u16* __restrict__ kb,
                                                      const u16* __restrict__ vT,
                                                      u16* __restrict__ att_out) {
    __shared__ __align__(16) u16 smem[2][16384];   // [buf][Ks 128*64 | Vs 64*128]
    const int tid = threadIdx.x;
    const int wave = tid >> 6, lane = tid & 63;
    const int quad = lane >> 4, l16 = lane & 15;
    const int qt = blockIdx.x, bh = blockIdx.y;
    const int b = bh >> 4, h = bh & 15;

    const u16* qrowA = &qb[(size_t)(bh * 2048 + qt * 128 + wave * 32 + l16) * 64];
    const bf16x8 qA0 = *(const bf16x8*)&qrowA[quad * 8];
    const bf16x8 qA1 = *(const bf16x8*)&qrowA[32 + quad * 8];
    const u16* qrowB = qrowA + 16 * 64;
    const bf16x8 qB0 = *(const bf16x8*)&qrowB[quad * 8];
    const bf16x8 qB1 = *(const bf16x8*)&qrowB[32 + quad * 8];

    const u16* ksrc[4];
    const u16* vsrc[4];
    int kofs[4], vofs[4];
    #pragma unroll
    for (int j = 0; j < 4; ++j) {
        const int p = 8 * wave + 32 * j + (lane >> 3);
        const int kr = (p & 0x60) | ((p & 12) << 1) | ((p & 16) >> 2) | (p & 3);
        const int gk = (lane & 7) ^ (p & 7);
        ksrc[j] = kb + ((size_t)bh * 2048 + kr) * 64 + gk * 8;
        kofs[j] = (8 * wave + 32 * j) * 64;
        const int d = 4 * wave + 16 * j + (lane >> 4);
        const int gv = (lane & 15) ^ (d & 15);
        vsrc[j] = vT + ((size_t)bh * 64 + d) * 2048 + gv * 8;
        vofs[j] = 8192 + (4 * wave + 16 * j) * 128;
    }

    f32x4 oA[4] = {}, oB[4] = {};
    f32x4 lA = {}, lB = {};
    bf16x8 ones;
    #pragma unroll
    for (int i = 0; i < 8; ++i) ones[i] = (__bf16)1.0f;

    #pragma unroll
    for (int j = 0; j < 4; ++j) {
        gload_lds16(ksrc[j], &smem[0][kofs[j]]);
        gload_lds16(vsrc[j], &smem[0][vofs[j]]);
        ksrc[j] += 128 * 64;
        vsrc[j] += 128;
    }

    for (int kt = 0; kt < 16; ++kt) {
        __syncthreads();
        if (kt < 15) {
            u16* nb_ = smem[(kt + 1) & 1];
            #pragma unroll
            for (int j = 0; j < 4; ++j) {
                gload_lds16(ksrc[j], &nb_[kofs[j]]);
                gload_lds16(vsrc[j], &nb_[vofs[j]]);
                ksrc[j] += 128 * 64;
                vsrc[j] += 128;
            }
        }
        const u16* Ks = smem[kt & 1];
        const u16* Vs = smem[kt & 1] + 8192;

        f32x4 sA[8] = {}, sB[8] = {};
        #pragma unroll
        for (int nt = 0; nt < 8; ++nt) {
            const int r = nt * 16 + l16;
            const bf16x8 k0 = *(const bf16x8*)&Ks[r * 64 + (((quad) ^ (r & 7)) << 3)];
            const bf16x8 k1 = *(const bf16x8*)&Ks[r * 64 + (((quad + 4) ^ (r & 7)) << 3)];
            sA[nt] = __builtin_amdgcn_mfma_f32_16x16x32_bf16(k0, qA0, sA[nt], 0, 0, 0);
            sA[nt] = __builtin_amdgcn_mfma_f32_16x16x32_bf16(k1, qA1, sA[nt], 0, 0, 0);
            sB[nt] = __builtin_amdgcn_mfma_f32_16x16x32_bf16(k0, qB0, sB[nt], 0, 0, 0);
            sB[nt] = __builtin_amdgcn_mfma_f32_16x16x32_bf16(k1, qB1, sB[nt], 0, 0, 0);
        }

        bf16x8 apA[4], apB[4];
        #pragma unroll
        for (int nt = 0; nt < 8; ++nt) {
            #pragma unroll
            for (int e = 0; e < 4; ++e) {
                apA[nt >> 1][(nt & 1) * 4 + e] = (__bf16)exp2f(sA[nt][e]);
                apB[nt >> 1][(nt & 1) * 4 + e] = (__bf16)exp2f(sB[nt][e]);
            }
        }

        #pragma unroll
        for (int vt = 0; vt < 4; ++vt) {
            const int dd = vt * 16 + l16;
            #pragma unroll
            for (int c = 0; c < 4; ++c) {
                const bf16x8 vf = *(const bf16x8*)&Vs[dd * 128 + (((c * 4 + quad) ^ l16) << 3)];
                oA[vt] = __builtin_amdgcn_mfma_f32_16x16x32_bf16(apA[c], vf, oA[vt], 0, 0, 0);
                oB[vt] = __builtin_amdgcn_mfma_f32_16x16x32_bf16(apB[c], vf, oB[vt], 0, 0, 0);
            }
        }
        #pragma unroll
        for (int c = 0; c < 4; ++c) {
            lA = __builtin_amdgcn_mfma_f32_16x16x32_bf16(apA[c], ones, lA, 0, 0, 0);
            lB = __builtin_amdgcn_mfma_f32_16x16x32_bf16(apB[c], ones, lB, 0, 0, 0);
        }
    }

    #pragma unroll
    for (int e = 0; e < 4; ++e) {
        const float invA = 1.0f / lA[e];
        const float invB = 1.0f / lB[e];
        const int nA = qt * 128 + wave * 32 + quad * 4 + e;
        #pragma unroll
        for (int vt = 0; vt < 4; ++vt) {
            att_out[(size_t)(b * 2048 + nA) * 1024 + h * 64 + vt * 16 + l16] = f2bf(oA[vt][e] * invA);
            att_out[(size_t)(b * 2048 + nA + 16) * 1024 + h * 64 + vt * 16 + l16] = f2bf(oB[vt][e] * invB);
        }
    }
}

// ---- GEMM2 (R6 two-barrier): att_out x wprojT + bias + z -> out fp32 ----
__global__ __launch_bounds__(256) void gemm_proj(const u16* __restrict__ A,
                                                 const u16* __restrict__ Bt,
                                                 const float* __restrict__ bias,
                                                 const float* __restrict__ z,
                                                 float* __restrict__ out) {
    __shared__ __align__(16) u16 As[64 * 32];
    __shared__ __align__(16) u16 Bs[128 * 32];
    const int tid = threadIdx.x;
    const int wave = tid >> 6, lane = tid & 63;
    const int quad = lane >> 4, l16 = lane & 15;
    const int wm = (wave >> 1) * 32, wn = (wave & 1) * 64;
    const int row0 = blockIdx.x * 64, col0 = blockIdx.y * 128;
    const int gr = lane >> 2, gc = (lane & 3) * 8;
    f32x4 acc[2][4] = {};
    for (int kt = 0; kt < 1024; kt += 32) {
        __syncthreads();
        gload_lds16(&A[(size_t)(row0 + wave * 16 + gr) * 1024 + kt + gc], &As[(wave * 16) * 32]);
        #pragma unroll
        for (int i = 0; i < 2; ++i) {
            const int rb = wave * 16 + i * 64;
            gload_lds16(&Bt[(size_t)(col0 + rb + gr) * 1024 + kt + gc], &Bs[rb * 32]);
        }
        __syncthreads();
        bf16x8 ax[2], bx[4];
        #pragma unroll
        for (int t = 0; t < 2; ++t)
            ax[t] = *(const bf16x8*)&As[(wm + t * 16 + l16) * 32 + quad * 8];
        #pragma unroll
        for (int t = 0; t < 4; ++t)
            bx[t] = *(const bf16x8*)&Bs[(wn + t * 16 + l16) * 32 + quad * 8];
        #pragma unroll
        for (int mt = 0; mt < 2; ++mt)
            #pragma unroll
            for (int nt = 0; nt < 4; ++nt)
                acc[mt][nt] = __builtin_amdgcn_mfma_f32_16x16x32_bf16(ax[mt], bx[nt], acc[mt][nt], 0, 0, 0);
    }
    #pragma unroll
    for (int mt = 0; mt < 2; ++mt) {
        #pragma unroll
        for (int nt = 0; nt < 4; ++nt) {
            #pragma unroll
            for (int e = 0; e < 4; ++e) {
                const int row = row0 + wm + mt * 16 + quad * 4 + e;
                const int col = col0 + wn + nt * 16 + l16;
                out[(size_t)row * 1024 + col] = acc[mt][nt][e] + bias[col] + z[(size_t)row * 1024 + col];
            }
        }
    }
}

extern "C" void kernel_launch(void* const* d_in, const int* in_sizes, int n_in,
                              void* d_out, int out_size, void* d_ws, size_t ws_size,
                              hipStream_t stream) {
    const float* z        = (const float*)d_in[0];
    const float* ln_scale = (const float*)d_in[1];
    const float* ln_bias  = (const float*)d_in[2];
    const float* w_qkv    = (const float*)d_in[3];
    const float* w_proj   = (const float*)d_in[4];
    const float* b_proj   = (const float*)d_in[5];
    float* out = (float*)d_out;

    char* ws = (char*)d_ws;
    u16* zn     = (u16*)(ws);                       // 0-8 MiB   [4096,1024]
    u16* wqkvT  = (u16*)(ws + (8u << 20));          // 8-14 MiB  [3072,1024] (rows permuted)
    u16* wprojT = (u16*)(ws + (14u << 20));         // 14-16 MiB [1024,1024]
    u16* qbuf   = (u16*)(ws + (16u << 20));         // 16-24 MiB [32,2048,64] (pre-scaled 0.125*log2e)
    u16* kbuf   = (u16*)(ws + (24u << 20));         // 24-32 MiB [32,2048,64]
    u16* vT     = (u16*)(ws + (32u << 20));         // 32-40 MiB [32,64,2048] (written by gemm_qkv)
    u16* att_o  = (u16*)(ws + (40u << 20));         // 40-48 MiB [4096,1024]

    prep_kernel<<<dim3(4096 + 3072 + 1024), 256, 0, stream>>>(
        z, ln_scale, ln_bias, w_qkv, w_proj, zn, wqkvT, wprojT);
    gemm_qkv<<<dim3(32, 24), 256, 0, stream>>>(zn, wqkvT, qbuf, kbuf, vT);
    attn_kernel<<<dim3(16, 32), 256, 0, stream>>>(qbuf, kbuf, vT, att_o);
    gemm_proj<<<dim3(64, 8), 256, 0, stream>>>(att_o, wprojT, b_proj, z, out);
}

// Round 16
// 189.112 us; speedup vs baseline: 1.1742x; 1.1742x over previous
//
#include <hip/hip_runtime.h>
#include <stdint.h>
#include <math.h>

typedef unsigned short u16;
typedef float f32x4 __attribute__((ext_vector_type(4)));
typedef __bf16 bf16x8 __attribute__((ext_vector_type(8)));

__device__ __forceinline__ u16 f2bf(float f) {
    union { float f; uint32_t u; } c; c.f = f;
    return (u16)((c.u + 0x7FFFu + ((c.u >> 16) & 1u)) >> 16);
}

__device__ __forceinline__ void gload_lds16(const void* g, void* l) {
    __builtin_amdgcn_global_load_lds(
        (const __attribute__((address_space(1))) unsigned int*)g,
        (__attribute__((address_space(3))) unsigned int*)l, 16, 0, 0);
}

// --------- fused prep: LN (blocks 0..4095) + w_qkv transpose (next 3072)
// --------- + w_proj transpose (last 1024). All roles block-uniform.
__global__ __launch_bounds__(256) void prep_kernel(const float* __restrict__ z,
                                                   const float* __restrict__ sc,
                                                   const float* __restrict__ bs,
                                                   const float* __restrict__ w_qkv,
                                                   const float* __restrict__ w_proj,
                                                   u16* __restrict__ zn,
                                                   u16* __restrict__ wqkvT,
                                                   u16* __restrict__ wprojT) {
    __shared__ float t[32][33];
    const int tid = threadIdx.x;
    const int bid = blockIdx.x;

    if (bid < 4096) {                      // ---- LayerNorm row
        float* red = &t[0][0];
        const int row = bid;
        const float4 v = ((const float4*)(z + (size_t)row * 1024))[tid];
        float s = v.x + v.y + v.z + v.w;
        #pragma unroll
        for (int off = 32; off > 0; off >>= 1) s += __shfl_xor(s, off);
        if ((tid & 63) == 0) red[tid >> 6] = s;
        __syncthreads();
        const float mean = (red[0] + red[1] + red[2] + red[3]) * (1.0f / 1024.0f);
        const float dx = v.x - mean, dy = v.y - mean, dz = v.z - mean, dw = v.w - mean;
        float q = dx * dx + dy * dy + dz * dz + dw * dw;
        #pragma unroll
        for (int off = 32; off > 0; off >>= 1) q += __shfl_xor(q, off);
        if ((tid & 63) == 0) red[4 + (tid >> 6)] = q;
        __syncthreads();
        const float var = (red[4] + red[5] + red[6] + red[7]) * (1.0f / 1024.0f);
        const float rstd = rsqrtf(var + 1e-5f);
        const float4 scv = ((const float4*)sc)[tid];
        const float4 bsv = ((const float4*)bs)[tid];
        const u16 o0 = f2bf(dx * rstd * scv.x + bsv.x);
        const u16 o1 = f2bf(dy * rstd * scv.y + bsv.y);
        const u16 o2 = f2bf(dz * rstd * scv.z + bsv.z);
        const u16 o3 = f2bf(dw * rstd * scv.w + bsv.w);
        uint2 pk;
        pk.x = (uint32_t)o0 | ((uint32_t)o1 << 16);
        pk.y = (uint32_t)o2 | ((uint32_t)o3 << 16);
        *(uint2*)&zn[(size_t)row * 1024 + tid * 4] = pk;
        return;
    }

    const float* in;
    u16* out;
    int K, N, permute, bx, by;
    if (bid < 4096 + 3072) {               // w_qkv: [1024,3072] -> permuted [3072,1024]
        const int r = bid - 4096;
        in = w_qkv; out = wqkvT; K = 1024; N = 3072; permute = 1;
        bx = r % 96; by = r / 96;
    } else {                               // w_proj: [1024,1024] -> [1024,1024]
        const int r = bid - 4096 - 3072;
        in = w_proj; out = wprojT; K = 1024; N = 1024; permute = 0;
        bx = r % 32; by = r / 32;
    }
    const int j = tid & 31, i0 = tid >> 5;
    const int kb = by * 32, nb = bx * 32;
    #pragma unroll
    for (int p = 0; p < 4; ++p) {
        int r = i0 + p * 8;
        t[r][j] = in[(size_t)(kb + r) * N + nb + j];
    }
    __syncthreads();
    #pragma unroll
    for (int p = 0; p < 4; ++p) {
        int r = i0 + p * 8;
        int c = nb + r;
        int np = c;
        if (permute) {
            int h = c / 192, rem = c - h * 192;
            int d = rem / 3, s = rem - d * 3;
            np = s * 1024 + h * 64 + d;
        }
        out[(size_t)np * K + kb + j] = f2bf(t[j][r]);
    }
}

// ---------------- GEMM1 (R6 two-barrier) + fused V transpose ---------------
// __launch_bounds__(256,3): pin 3 blocks/CU (R15's fusion pushed the unified
// VGPR+AGPR budget over the 3-block boundary -> MfmaUtil 22->14.6%).
// Q/K epilogue: coalesced [bh,n,d] stores (q pre-scaled 0.125*log2e).
// V epilogue (s==2): acc tile round-trips through padded LDS (stride 136) and
// stores straight to vT[bh,d,n] with 16B writes; writes packed as ds_write_b64.
__global__ __launch_bounds__(256, 3) void gemm_qkv(const u16* __restrict__ A,
                                                   const u16* __restrict__ Bt,
                                                   u16* __restrict__ qbuf,
                                                   u16* __restrict__ kbuf,
                                                   u16* __restrict__ vT) {
    __shared__ __align__(16) u16 sm[64 * 136];   // 17.4 KB; main loop uses [0,8192)
    u16* const As = sm;                           // 128*32
    u16* const Bs = sm + 4096;                    // 128*32
    const int tid = threadIdx.x;
    const int wave = tid >> 6, lane = tid & 63;
    const int quad = lane >> 4, l16 = lane & 15;
    const int wm = (wave >> 1) * 64, wn = (wave & 1) * 64;
    const int row0 = blockIdx.x * 128, col0 = blockIdx.y * 128;
    const int gr = lane >> 2, gc = (lane & 3) * 8;
    f32x4 acc[4][4] = {};
    for (int kt = 0; kt < 1024; kt += 32) {
        __syncthreads();
        #pragma unroll
        for (int i = 0; i < 2; ++i) {
            const int rb = wave * 16 + i * 64;
            gload_lds16(&A[(size_t)(row0 + rb + gr) * 1024 + kt + gc], &As[rb * 32]);
            gload_lds16(&Bt[(size_t)(col0 + rb + gr) * 1024 + kt + gc], &Bs[rb * 32]);
        }
        __syncthreads();
        bf16x8 ax[4], bx[4];
        #pragma unroll
        for (int t = 0; t < 4; ++t) {
            ax[t] = *(const bf16x8*)&As[(wm + t * 16 + l16) * 32 + quad * 8];
            bx[t] = *(const bf16x8*)&Bs[(wn + t * 16 + l16) * 32 + quad * 8];
        }
        #pragma unroll
        for (int mt = 0; mt < 4; ++mt)
            #pragma unroll
            for (int nt = 0; nt < 4; ++nt)
                acc[mt][nt] = __builtin_amdgcn_mfma_f32_16x16x32_bf16(ax[mt], bx[nt], acc[mt][nt], 0, 0, 0);
    }
    const int s = col0 >> 10;                 // block-uniform
    if (s < 2) {
        u16* const dst = (s == 0) ? qbuf : kbuf;
        const float scl = (s == 0) ? 0.125f * 1.44269504088896f : 1.0f;
        #pragma unroll
        for (int mt = 0; mt < 4; ++mt) {
            #pragma unroll
            for (int nt = 0; nt < 4; ++nt) {
                #pragma unroll
                for (int e = 0; e < 4; ++e) {
                    const int row = row0 + wm + mt * 16 + quad * 4 + e;
                    const int col = col0 + wn + nt * 16 + l16;
                    const int b = row >> 11, n = row & 2047;
                    const int h = (col >> 6) & 15, d = col & 63;
                    dst[((size_t)(b * 16 + h) * 2048 + n) * 64 + d] = f2bf(acc[mt][nt][e] * scl);
                }
            }
        }
    } else {
        // V: transpose 128x128 tile through LDS, store to vT[bh,d,n].
        const int b = row0 >> 11, n0 = row0 & 2047;
        const int h0 = (col0 >> 6) & 15;          // col0 = 2048 + cb*128 -> h0 = 2*cb
        for (int hh = 0; hh < 2; ++hh) {
            __syncthreads();                      // tile buffer free (main loop / prev pass done)
            if ((wave & 1) == hh) {               // wn == hh*64 waves own this col-half
                #pragma unroll
                for (int mt = 0; mt < 4; ++mt) {
                    const int rl = wm + mt * 16 + quad * 4;       // multiple of 4 -> 8B aligned
                    #pragma unroll
                    for (int nt = 0; nt < 4; ++nt) {
                        const int cl = nt * 16 + l16;             // d 0..63
                        u16 tmp[4];
                        #pragma unroll
                        for (int e = 0; e < 4; ++e) tmp[e] = f2bf(acc[mt][nt][e]);
                        *(uint2*)&sm[cl * 136 + rl] = *(const uint2*)tmp;   // ds_write_b64
                    }
                }
            }
            __syncthreads();
            const int bh = b * 16 + h0 + hh;
            #pragma unroll
            for (int pass = 0; pass < 4; ++pass) {
                const int chunk = pass * 256 + tid;   // 0..1023
                const int d = chunk >> 4;             // 0..63
                const int nc = chunk & 15;            // 16 chunks of 8 n
                const uint4 vv = *(const uint4*)&sm[d * 136 + nc * 8];
                *(uint4*)&vT[((size_t)bh * 64 + d) * 2048 + n0 + nc * 8] = vv;
            }
        }
    }
}

// ---------------- Fused flash attention (R9 proven: R6 + VGPR hint) ---------
// 128-q blocks (4 waves, 32 q each), 128-key tiles, K+V LDS dbuf (64 KB),
// one barrier/tile; stage(kt+1) flies over compute(kt). Maxless softmax
// (q pre-scaled 0.125*log2e, P=exp2(S)); denominator via MFMA against ones.
// kr-permuted K rows + XOR chunk swizzle: exp'd S^T C-layout values are the
// PV A-fragment in-lane; all LDS accesses conflict-free.
__global__ __launch_bounds__(256, 2) void attn_kernel(const u16* __restrict__ qb,
                                                      const u16* __restrict__ kb,
                                                      const u16* __restrict__ vT,
                                                      u16* __restrict__ att_out) {
    __shared__ __align__(16) u16 smem[2][16384];   // [buf][Ks 128*64 | Vs 64*128]
    const int tid = threadIdx.x;
    const int wave = tid >> 6, lane = tid & 63;
    const int quad = lane >> 4, l16 = lane & 15;
    const int qt = blockIdx.x, bh = blockIdx.y;
    const int b = bh >> 4, h = bh & 15;

    const u16* qrowA = &qb[(size_t)(bh * 2048 + qt * 128 + wave * 32 + l16) * 64];
    const bf16x8 qA0 = *(const bf16x8*)&qrowA[quad * 8];
    const bf16x8 qA1 = *(const bf16x8*)&qrowA[32 + quad * 8];
    const u16* qrowB = qrowA + 16 * 64;
    const bf16x8 qB0 = *(const bf16x8*)&qrowB[quad * 8];
    const bf16x8 qB1 = *(const bf16x8*)&qrowB[32 + quad * 8];

    const u16* ksrc[4];
    const u16* vsrc[4];
    int kofs[4], vofs[4];
    #pragma unroll
    for (int j = 0; j < 4; ++j) {
        const int p = 8 * wave + 32 * j + (lane >> 3);
        const int kr = (p & 0x60) | ((p & 12) << 1) | ((p & 16) >> 2) | (p & 3);
        const int gk = (lane & 7) ^ (p & 7);
        ksrc[j] = kb + ((size_t)bh * 2048 + kr) * 64 + gk * 8;
        kofs[j] = (8 * wave + 32 * j) * 64;
        const int d = 4 * wave + 16 * j + (lane >> 4);
        const int gv = (lane & 15) ^ (d & 15);
        vsrc[j] = vT + ((size_t)bh * 64 + d) * 2048 + gv * 8;
        vofs[j] = 8192 + (4 * wave + 16 * j) * 128;
    }

    f32x4 oA[4] = {}, oB[4] = {};
    f32x4 lA = {}, lB = {};
    bf16x8 ones;
    #pragma unroll
    for (int i = 0; i < 8; ++i) ones[i] = (__bf16)1.0f;

    #pragma unroll
    for (int j = 0; j < 4; ++j) {
        gload_lds16(ksrc[j], &smem[0][kofs[j]]);
        gload_lds16(vsrc[j], &smem[0][vofs[j]]);
        ksrc[j] += 128 * 64;
        vsrc[j] += 128;
    }

    for (int kt = 0; kt < 16; ++kt) {
        __syncthreads();
        if (kt < 15) {
            u16* nb_ = smem[(kt + 1) & 1];
            #pragma unroll
            for (int j = 0; j < 4; ++j) {
                gload_lds16(ksrc[j], &nb_[kofs[j]]);
                gload_lds16(vsrc[j], &nb_[vofs[j]]);
                ksrc[j] += 128 * 64;
                vsrc[j] += 128;
            }
        }
        const u16* Ks = smem[kt & 1];
        const u16* Vs = smem[kt & 1] + 8192;

        f32x4 sA[8] = {}, sB[8] = {};
        #pragma unroll
        for (int nt = 0; nt < 8; ++nt) {
            const int r = nt * 16 + l16;
            const bf16x8 k0 = *(const bf16x8*)&Ks[r * 64 + (((quad) ^ (r & 7)) << 3)];
            const bf16x8 k1 = *(const bf16x8*)&Ks[r * 64 + (((quad + 4) ^ (r & 7)) << 3)];
            sA[nt] = __builtin_amdgcn_mfma_f32_16x16x32_bf16(k0, qA0, sA[nt], 0, 0, 0);
            sA[nt] = __builtin_amdgcn_mfma_f32_16x16x32_bf16(k1, qA1, sA[nt], 0, 0, 0);
            sB[nt] = __builtin_amdgcn_mfma_f32_16x16x32_bf16(k0, qB0, sB[nt], 0, 0, 0);
            sB[nt] = __builtin_amdgcn_mfma_f32_16x16x32_bf16(k1, qB1, sB[nt], 0, 0, 0);
        }

        bf16x8 apA[4], apB[4];
        #pragma unroll
        for (int nt = 0; nt < 8; ++nt) {
            #pragma unroll
            for (int e = 0; e < 4; ++e) {
                apA[nt >> 1][(nt & 1) * 4 + e] = (__bf16)exp2f(sA[nt][e]);
                apB[nt >> 1][(nt & 1) * 4 + e] = (__bf16)exp2f(sB[nt][e]);
            }
        }

        #pragma unroll
        for (int vt = 0; vt < 4; ++vt) {
            const int dd = vt * 16 + l16;
            #pragma unroll
            for (int c = 0; c < 4; ++c) {
                const bf16x8 vf = *(const bf16x8*)&Vs[dd * 128 + (((c * 4 + quad) ^ l16) << 3)];
                oA[vt] = __builtin_amdgcn_mfma_f32_16x16x32_bf16(apA[c], vf, oA[vt], 0, 0, 0);
                oB[vt] = __builtin_amdgcn_mfma_f32_16x16x32_bf16(apB[c], vf, oB[vt], 0, 0, 0);
            }
        }
        #pragma unroll
        for (int c = 0; c < 4; ++c) {
            lA = __builtin_amdgcn_mfma_f32_16x16x32_bf16(apA[c], ones, lA, 0, 0, 0);
            lB = __builtin_amdgcn_mfma_f32_16x16x32_bf16(apB[c], ones, lB, 0, 0, 0);
        }
    }

    #pragma unroll
    for (int e = 0; e < 4; ++e) {
        const float invA = 1.0f / lA[e];
        const float invB = 1.0f / lB[e];
        const int nA = qt * 128 + wave * 32 + quad * 4 + e;
        #pragma unroll
        for (int vt = 0; vt < 4; ++vt) {
            att_out[(size_t)(b * 2048 + nA) * 1024 + h * 64 + vt * 16 + l16] = f2bf(oA[vt][e] * invA);
            att_out[(size_t)(b * 2048 + nA + 16) * 1024 + h * 64 + vt * 16 + l16] = f2bf(oB[vt][e] * invB);
        }
    }
}

// ---- GEMM2 (R6 two-barrier): att_out x wprojT + bias + z -> out fp32 ----
__global__ __launch_bounds__(256) void gemm_proj(const u16* __restrict__ A,
                                                 const u16* __restrict__ Bt,
                                                 const float* __restrict__ bias,
                                                 const float* __restrict__ z,
                                                 float* __restrict__ out) {
    __shared__ __align__(16) u16 As[64 * 32];
    __shared__ __align__(16) u16 Bs[128 * 32];
    const int tid = threadIdx.x;
    const int wave = tid >> 6, lane = tid & 63;
    const int quad = lane >> 4, l16 = lane & 15;
    const int wm = (wave >> 1) * 32, wn = (wave & 1) * 64;
    const int row0 = blockIdx.x * 64, col0 = blockIdx.y * 128;
    const int gr = lane >> 2, gc = (lane & 3) * 8;
    f32x4 acc[2][4] = {};
    for (int kt = 0; kt < 1024; kt += 32) {
        __syncthreads();
        gload_lds16(&A[(size_t)(row0 + wave * 16 + gr) * 1024 + kt + gc], &As[(wave * 16) * 32]);
        #pragma unroll
        for (int i = 0; i < 2; ++i) {
            const int rb = wave * 16 + i * 64;
            gload_lds16(&Bt[(size_t)(col0 + rb + gr) * 1024 + kt + gc], &Bs[rb * 32]);
        }
        __syncthreads();
        bf16x8 ax[2], bx[4];
        #pragma unroll
        for (int t = 0; t < 2; ++t)
            ax[t] = *(const bf16x8*)&As[(wm + t * 16 + l16) * 32 + quad * 8];
        #pragma unroll
        for (int t = 0; t < 4; ++t)
            bx[t] = *(const bf16x8*)&Bs[(wn + t * 16 + l16) * 32 + quad * 8];
        #pragma unroll
        for (int mt = 0; mt < 2; ++mt)
            #pragma unroll
            for (int nt = 0; nt < 4; ++nt)
                acc[mt][nt] = __builtin_amdgcn_mfma_f32_16x16x32_bf16(ax[mt], bx[nt], acc[mt][nt], 0, 0, 0);
    }
    #pragma unroll
    for (int mt = 0; mt < 2; ++mt) {
        #pragma unroll
        for (int nt = 0; nt < 4; ++nt) {
            #pragma unroll
            for (int e = 0; e < 4; ++e) {
                const int row = row0 + wm + mt * 16 + quad * 4 + e;
                const int col = col0 + wn + nt * 16 + l16;
                out[(size_t)row * 1024 + col] = acc[mt][nt][e] + bias[col] + z[(size_t)row * 1024 + col];
            }
        }
    }
}

extern "C" void kernel_launch(void* const* d_in, const int* in_sizes, int n_in,
                              void* d_out, int out_size, void* d_ws, size_t ws_size,
                              hipStream_t stream) {
    const float* z        = (const float*)d_in[0];
    const float* ln_scale = (const float*)d_in[1];
    const float* ln_bias  = (const float*)d_in[2];
    const float* w_qkv    = (const float*)d_in[3];
    const float* w_proj   = (const float*)d_in[4];
    const float* b_proj   = (const float*)d_in[5];
    float* out = (float*)d_out;

    char* ws = (char*)d_ws;
    u16* zn     = (u16*)(ws);                       // 0-8 MiB   [4096,1024]
    u16* wqkvT  = (u16*)(ws + (8u << 20));          // 8-14 MiB  [3072,1024] (rows permuted)
    u16* wprojT = (u16*)(ws + (14u << 20));         // 14-16 MiB [1024,1024]
    u16* qbuf   = (u16*)(ws + (16u << 20));         // 16-24 MiB [32,2048,64] (pre-scaled 0.125*log2e)
    u16* kbuf   = (u16*)(ws + (24u << 20));         // 24-32 MiB [32,2048,64]
    u16* vT     = (u16*)(ws + (32u << 20));         // 32-40 MiB [32,64,2048] (written by gemm_qkv)
    u16* att_o  = (u16*)(ws + (40u << 20));         // 40-48 MiB [4096,1024]

    prep_kernel<<<dim3(4096 + 3072 + 1024), 256, 0, stream>>>(
        z, ln_scale, ln_bias, w_qkv, w_proj, zn, wqkvT, wprojT);
    gemm_qkv<<<dim3(32, 24), 256, 0, stream>>>(zn, wqkvT, qbuf, kbuf, vT);
    attn_kernel<<<dim3(16, 32), 256, 0, stream>>>(qbuf, kbuf, vT, att_o);
    gemm_proj<<<dim3(64, 8), 256, 0, stream>>>(att_o, wprojT, b_proj, z, out);
}